// Round 11
// baseline (318.642 us; speedup 1.0000x reference)
//
#include <hip/hip_runtime.h>
#include <hip/hip_bf16.h>
#include <stdint.h>

#define N_NODES 50000
#define N_EDGES 800000
#define D_H 128
#define D_E 64
#define HID 128

#define MTILE 96
#define SMAX 16
#define N_ETILES ((N_EDGES + MTILE - 1) / MTILE)     // 8334
#define TPB 4                                        // tiles per block
#define N_EBLK ((N_ETILES + TPB - 1) / TPB)          // 2084

#define SCAN_B 512
#define N_CHUNKS ((N_NODES + SCAN_B - 1) / SCAN_B)   // 98

typedef __attribute__((ext_vector_type(8))) short bf16x8;
typedef __attribute__((ext_vector_type(4))) short s16x4;
typedef __attribute__((ext_vector_type(4))) float f32x4;
typedef __attribute__((ext_vector_type(4))) int i32x4;

__device__ __forceinline__ unsigned short f2bf(float x) {
    unsigned int u = __float_as_uint(x);
    u += 0x7FFFu + ((u >> 16) & 1u);   // round-to-nearest-even
    return (unsigned short)(u >> 16);
}

__device__ __forceinline__ s16x4 pack4(const f32x4 v) {
    s16x4 o = { (short)f2bf(v[0]), (short)f2bf(v[1]),
                (short)f2bf(v[2]), (short)f2bf(v[3]) };
    return o;
}

// ---------------- zero: gmax (f32) + deg ----------------
#define NG4 (N_NODES * HID / 4)
#define ND4 (N_NODES / 4)
__global__ void zero_ws(float* __restrict__ gmax, int* __restrict__ deg) {
    const int i = blockIdx.x * blockDim.x + threadIdx.x;
    if (i < NG4) {
        ((f32x4*)gmax)[i] = f32x4{0.f, 0.f, 0.f, 0.f};
    } else if (i < NG4 + ND4) {
        ((i32x4*)deg)[i - NG4] = i32x4{0, 0, 0, 0};
    }
}

// ---------------- converts: Hb + W1t + W2t ----------------
#define NHB4 (N_NODES * D_H / 4)
#define NW1 (192 * HID)
#define NW2 (256 * HID)
__global__ void conv_aux(const float* __restrict__ H,
                         const float* __restrict__ W1,
                         const float* __restrict__ W2,
                         unsigned short* __restrict__ Hb,
                         unsigned short* __restrict__ W1t,
                         unsigned short* __restrict__ W2t) {
    const int i = blockIdx.x * blockDim.x + threadIdx.x;
    if (i < NHB4) {
        ((s16x4*)Hb)[i] = pack4(((const f32x4*)H)[i]);
    } else if (i < NHB4 + NW1) {                     // W1t [128][192] bf16
        const int j = i - NHB4;
        const int n = j / 192, k = j - n * 192;
        W1t[j] = f2bf(W1[k * HID + n]);
    } else if (i < NHB4 + NW1 + NW2) {               // W2t [128][256] bf16
        const int j = i - NHB4 - NW1;
        const int n = j >> 8, k = j & 255;
        W2t[j] = f2bf(W2[k * HID + n]);
    }
}

// ---------------- histogram ----------------
__global__ void hist(const int* __restrict__ idx, int* __restrict__ deg) {
    const int i = blockIdx.x * blockDim.x + threadIdx.x;
    atomicAdd(&deg[idx[N_EDGES + i]], 1);
}

// ---------------- 3-kernel parallel exclusive scan ----------------
__global__ void scan_a(const int* __restrict__ deg, int* __restrict__ sc,
                       int* __restrict__ totals) {
    __shared__ int s[SCAN_B];
    const int tid = threadIdx.x;
    const int i = blockIdx.x * SCAN_B + tid;
    const int v = (i < N_NODES) ? deg[i] : 0;
    s[tid] = v;
    __syncthreads();
    for (int o = 1; o < SCAN_B; o <<= 1) {
        int t = (tid >= o) ? s[tid - o] : 0;
        __syncthreads();
        s[tid] += t;
        __syncthreads();
    }
    if (i < N_NODES) sc[i] = s[tid] - v;
    if (tid == SCAN_B - 1) totals[blockIdx.x] = s[SCAN_B - 1];
}

__global__ void scan_b(int* __restrict__ totals) {
    __shared__ int s[128];
    const int tid = threadIdx.x;
    const int v = (tid < N_CHUNKS) ? totals[tid] : 0;
    s[tid] = v;
    __syncthreads();
    for (int o = 1; o < 128; o <<= 1) {
        int t = (tid >= o) ? s[tid - o] : 0;
        __syncthreads();
        s[tid] += t;
        __syncthreads();
    }
    if (tid < N_CHUNKS) totals[tid] = s[tid] - v;
}

__global__ void scan_c(const int* __restrict__ sc, const int* __restrict__ totals,
                       int* __restrict__ cursor) {
    const int i = blockIdx.x * SCAN_B + threadIdx.x;
    if (i < N_NODES) cursor[i] = sc[i] + totals[blockIdx.x];
}

// ---------------- scatter: one packed 8B store per edge ----------------
__global__ void scatter(const int* __restrict__ idx, int* __restrict__ cursor,
                        unsigned long long* __restrict__ pk8) {
    int i = blockIdx.x * blockDim.x + threadIdx.x;
    const int s = idx[i];
    const int d = idx[N_EDGES + i];
    const int p = atomicAdd(&cursor[d], 1);
    pk8[p] = (unsigned long long)(unsigned)i |
             ((unsigned long long)(unsigned)s << 20) |
             ((unsigned long long)(unsigned)d << 37);
}

// ---------------- edge MLP: 4-tile loop per block, 512 thr, pipelined ----------------
// Per-tile phases (LDS ordering audit):
//   (a) meta(t+1) -> sMeta[bb^1]; flags(t) from dCur; lane0 -> sWaveTot   [pre-A]
//   (b) ds_write regs -> sX(t)                                           [pre-A]
//   (A) barrier: publishes sX, sWaveTot, meta(t+1)
//   (d) g/rowG/segNode(t); nSegR -> REGISTER; issueGather(t+1)           [A..B]
//   (B) barrier: publishes rowG/segNode
//   (f) MFMA reads sX; reduce -> ymax atomics                            [B..C]
//   (C) barrier: ymax complete
//   (h) writeout uses nSegR(reg), segNode, ymax; rezero ymax rows < nS   [post-C]
// Races closed vs R10: sWaveTot read only in (d) (after A, before next write
// which is post-C); nSeg kept in a register so (h) never reads sWaveTot.
__global__ __launch_bounds__(512, 4)
void edge_sorted(const float* __restrict__ H,
                 const unsigned short* __restrict__ Hb,
                 const float* __restrict__ Xe,
                 const float* __restrict__ W1,
                 const unsigned short* __restrict__ W1t,
                 const unsigned long long* __restrict__ pk8,
                 float* __restrict__ gmax, int useAux) {
    __shared__ unsigned short sX[MTILE][200];        // 38.4 KB
    __shared__ float ymax[SMAX][132];                // 8.45 KB
    __shared__ int sMetaE[2][MTILE];
    __shared__ int sMetaS[2][MTILE];
    __shared__ int sMetaD[2][MTILE];
    __shared__ int segNode[SMAX];
    __shared__ int sWaveTot[8];
    __shared__ unsigned char rowG[MTILE];

    const int tid  = threadIdx.x;
    const int wave = tid >> 6;
    const int lane = tid & 63;
    const int t0   = blockIdx.x * TPB;
    const int nT   = (N_ETILES - t0 < TPB) ? (N_ETILES - t0) : TPB;

    const int col  = lane & 15;
    const int kr0  = (lane >> 4) * 8;
    const int arow = lane & 15;
    const int rb   = (lane >> 4) * 4;
    const int cb   = wave * 16 + col;

    // --- B fragment (W1): once per block, amortized over nT tiles
    bf16x8 bfrag[6];
    if (useAux) {
        #pragma unroll
        for (int ks = 0; ks < 6; ++ks)
            bfrag[ks] = *(const bf16x8*)&W1t[(size_t)cb * 192 + ks * 32 + kr0];
    } else {
        #pragma unroll
        for (int ks = 0; ks < 6; ++ks) {
            const int kb = ks * 32 + kr0;
            bf16x8 b;
            #pragma unroll
            for (int f = 0; f < 8; ++f) b[f] = (short)f2bf(W1[(kb + f) * HID + cb]);
            bfrag[ks] = b;
        }
    }

    for (int i2 = tid; i2 < SMAX * 132; i2 += 512) ((float*)ymax)[i2] = 0.f;

    // --- prologue: meta(0) -> buf0
    int dCur = 0, dNext = 0;
    if (tid < MTILE) {
        int pe = t0 * MTILE + tid;
        if (pe >= N_EDGES) pe = N_EDGES - 1;
        const unsigned long long w = pk8[pe];
        sMetaE[0][tid] = (int)(w & 0xFFFFFull);
        sMetaS[0][tid] = (int)((w >> 20) & 0x1FFFFull);
        sMetaD[0][tid] = (int)(w >> 37);
        dCur = (int)(w >> 37);
    }
    __syncthreads();                                  // meta(0) + ymax zero visible

    bf16x8 hb[3];      // useAux gather hold
    f32x4  hraw[6];    // !useAux gather hold
    f32x4  xer[3];     // Xe gather hold

    auto issueGather = [&](int bb) {
        if (useAux) {
            #pragma unroll
            for (int it = 0; it < 3; ++it) {
                const int j = tid + it * 512, row = j >> 4, c8 = (j & 15) * 8;
                hb[it] = *(const bf16x8*)(Hb + (size_t)sMetaS[bb][row] * D_H + c8);
            }
        } else {
            #pragma unroll
            for (int it = 0; it < 6; ++it) {
                const int j = tid + it * 512, row = j >> 5, c4 = (j & 31) * 4;
                hraw[it] = *(const f32x4*)(H + (size_t)sMetaS[bb][row] * D_H + c4);
            }
        }
        #pragma unroll
        for (int it = 0; it < 3; ++it) {
            const int j = tid + it * 512, row = j >> 4, c4 = (j & 15) * 4;
            xer[it] = *(const f32x4*)(Xe + (size_t)sMetaE[bb][row] * D_E + c4);
        }
    };
    issueGather(0);

    for (int t = 0; t < nT; ++t) {
        const int bb = t & 1;
        const int gt = t0 + t;

        // --- (a) meta(t+1) + flags(t) + sWaveTot
        const bool inTile = (tid < MTILE);
        const bool valid  = inTile && (gt * MTILE + tid < N_EDGES);
        if (t + 1 < nT && inTile) {
            int pe = (gt + 1) * MTILE + tid;
            if (pe >= N_EDGES) pe = N_EDGES - 1;
            const unsigned long long w = pk8[pe];
            sMetaE[bb ^ 1][tid] = (int)(w & 0xFFFFFull);
            sMetaS[bb ^ 1][tid] = (int)((w >> 20) & 0x1FFFFull);
            sMetaD[bb ^ 1][tid] = (int)(w >> 37);
            dNext = (int)(w >> 37);
        }
        int dp = __shfl_up(dCur, 1);
        if (lane == 0 && tid == 64) dp = sMetaD[bb][63];  // wave-boundary (bufs differ, no race)
        const bool flag = valid && (tid == 0 || dCur != dp);
        const unsigned long long m = __ballot(flag);
        if (lane == 0) sWaveTot[wave] = (int)__popcll(m);

        // --- (b) ds_write staged regs -> sX(t)
        if (useAux) {
            #pragma unroll
            for (int it = 0; it < 3; ++it) {
                const int j = tid + it * 512, row = j >> 4, c8 = (j & 15) * 8;
                *(bf16x8*)&sX[row][c8] = hb[it];
            }
        } else {
            #pragma unroll
            for (int it = 0; it < 6; ++it) {
                const int j = tid + it * 512, row = j >> 5, c4 = (j & 31) * 4;
                *(s16x4*)&sX[row][c4] = pack4(hraw[it]);
            }
        }
        #pragma unroll
        for (int it = 0; it < 3; ++it) {
            const int j = tid + it * 512, row = j >> 4, c4 = (j & 15) * 4;
            *(s16x4*)&sX[row][128 + c4] = pack4(xer[it]);
        }
        __syncthreads();                              // A

        // --- (d) segment ids (tile t) + capture nSeg + prefetch gathers(t+1)
        const int nSegR = sWaveTot[0] + sWaveTot[1];
        int g = 255;
        if (valid) {
            const unsigned long long le =
                (lane == 63) ? ~0ull : ((1ull << (lane + 1)) - 1);
            g = (int)__popcll(m & le) - 1 + ((wave == 1) ? sWaveTot[0] : 0);
        }
        if (inTile) rowG[tid] = (unsigned char)(valid ? g : 255);
        if (flag && g < SMAX) segNode[g] = dCur;
        if (t + 1 < nT) issueGather(bb ^ 1);
        dCur = dNext;
        __syncthreads();                              // B

        // --- (f) MFMA: 96 x 192 @ 192 x 16 per wave
        f32x4 acc[6];
        #pragma unroll
        for (int mm = 0; mm < 6; ++mm) acc[mm] = f32x4{0.f, 0.f, 0.f, 0.f};
        __builtin_amdgcn_s_setprio(1);
        #pragma unroll
        for (int ks = 0; ks < 6; ++ks)
            #pragma unroll
            for (int mm = 0; mm < 6; ++mm) {
                bf16x8 a = *(const bf16x8*)&sX[mm * 16 + arow][ks * 32 + kr0];
                acc[mm] = __builtin_amdgcn_mfma_f32_16x16x32_bf16(a, bfrag[ks], acc[mm], 0, 0, 0);
            }
        __builtin_amdgcn_s_setprio(0);

        // --- relu + segmented max into LDS (overflow -> direct global atomics)
        #pragma unroll
        for (int mm = 0; mm < 6; ++mm) {
            const int r0 = mm * 16 + rb;
            const int q0 = rowG[r0];
            const int q3 = rowG[r0 + 3];
            if (q0 == q3) {
                const float v0 = fmaxf(fmaxf(acc[mm][0], acc[mm][1]),
                                       fmaxf(acc[mm][2], acc[mm][3]));
                if (q0 < SMAX) {
                    if (v0 > 0.f) atomicMax((int*)&ymax[q0][cb], __float_as_int(v0));
                } else if (q0 < 255) {
                    if (v0 > 0.f)
                        atomicMax((int*)(gmax + (size_t)sMetaD[bb][r0] * HID + cb),
                                  __float_as_int(v0));
                }
            } else {
                #pragma unroll
                for (int r = 0; r < 4; ++r) {
                    const int qq = rowG[r0 + r];
                    const float v0 = acc[mm][r];
                    if (qq < SMAX) {
                        if (v0 > 0.f) atomicMax((int*)&ymax[qq][cb], __float_as_int(v0));
                    } else if (qq < 255) {
                        if (v0 > 0.f)
                            atomicMax((int*)(gmax + (size_t)sMetaD[bb][r0 + r] * HID + cb),
                                      __float_as_int(v0));
                    }
                }
            }
        }
        __syncthreads();                              // C

        // --- (h) writeout (vectorized interior) + fused rezero; uses REGISTER nSegR
        const int nS = (nSegR < SMAX) ? nSegR : SMAX;
        for (int i2 = tid; i2 < nS * 32; i2 += 512) {
            const int sg = i2 >> 5;
            const int c4 = (i2 & 31) * 4;
            float* dst = gmax + (size_t)segNode[sg] * HID + c4;
            f32x4 v = *(f32x4*)&ymax[sg][c4];
            *(f32x4*)&ymax[sg][c4] = f32x4{0.f, 0.f, 0.f, 0.f};
            if (sg == 0 || sg == nSegR - 1) {
                #pragma unroll
                for (int q = 0; q < 4; ++q)
                    if (v[q] > 0.f) atomicMax((int*)(dst + q), __float_as_int(v[q]));
            } else {
                *(f32x4*)dst = v;
            }
        }
    }
}

// ---------------- node MLP + residual ----------------
__global__ __launch_bounds__(256, 4)
void node_mlp(const float* __restrict__ H,
              const float* __restrict__ gmax,
              const float* __restrict__ W2,
              const unsigned short* __restrict__ W2t,
              float* __restrict__ out, int useAux) {
    __shared__ unsigned short sA[64][264];

    const int tid  = threadIdx.x;
    const int wave = tid >> 6;
    const int lane = tid & 63;
    const int base = blockIdx.x * 64;

    const int col = lane & 15;
    const int kr0 = (lane >> 4) * 8;
    bf16x8 bfrag[8][2];
    if (useAux) {
        #pragma unroll
        for (int ks = 0; ks < 8; ++ks)
            #pragma unroll
            for (int nf = 0; nf < 2; ++nf) {
                const int n = wave * 32 + nf * 16 + col;
                bfrag[ks][nf] = *(const bf16x8*)&W2t[(size_t)n * 256 + ks * 32 + kr0];
            }
    } else {
        #pragma unroll
        for (int ks = 0; ks < 8; ++ks)
            #pragma unroll
            for (int nf = 0; nf < 2; ++nf) {
                const int n  = wave * 32 + nf * 16 + col;
                const int kb = ks * 32 + kr0;
                bf16x8 b;
                #pragma unroll
                for (int f = 0; f < 8; ++f) b[f] = (short)f2bf(W2[(kb + f) * HID + n]);
                bfrag[ks][nf] = b;
            }
    }

    #pragma unroll
    for (int it = 0; it < 8; ++it) {
        const int i   = tid + it * 256;
        const int row = i >> 5;
        const int c4  = (i & 31) * 4;
        int node = base + row;
        if (node >= N_NODES) node = N_NODES - 1;
        *(s16x4*)&sA[row][c4] = pack4(*(const f32x4*)(H + (size_t)node * D_H + c4));
    }
    #pragma unroll
    for (int it = 0; it < 8; ++it) {
        const int i   = tid + it * 256;
        const int row = i >> 5;
        const int c4  = (i & 31) * 4;
        int node = base + row;
        if (node >= N_NODES) node = N_NODES - 1;
        *(s16x4*)&sA[row][128 + c4] = pack4(*(const f32x4*)(gmax + (size_t)node * HID + c4));
    }
    __syncthreads();

    f32x4 acc[4][2];
    #pragma unroll
    for (int mm = 0; mm < 4; ++mm) {
        acc[mm][0] = f32x4{0.f, 0.f, 0.f, 0.f};
        acc[mm][1] = f32x4{0.f, 0.f, 0.f, 0.f};
    }
    const int arow = lane & 15;
    __builtin_amdgcn_s_setprio(1);
    #pragma unroll
    for (int ks = 0; ks < 8; ++ks)
        #pragma unroll
        for (int mm = 0; mm < 4; ++mm) {
            bf16x8 a = *(const bf16x8*)&sA[mm * 16 + arow][ks * 32 + kr0];
            acc[mm][0] = __builtin_amdgcn_mfma_f32_16x16x32_bf16(a, bfrag[ks][0], acc[mm][0], 0, 0, 0);
            acc[mm][1] = __builtin_amdgcn_mfma_f32_16x16x32_bf16(a, bfrag[ks][1], acc[mm][1], 0, 0, 0);
        }
    __builtin_amdgcn_s_setprio(0);

    const int rb = (lane >> 4) * 4;
    #pragma unroll
    for (int mm = 0; mm < 4; ++mm)
        #pragma unroll
        for (int r = 0; r < 4; ++r) {
            const int node = base + mm * 16 + rb + r;
            if (node < N_NODES) {
                const size_t o = (size_t)node * HID + wave * 32 + col;
                out[o]      = fmaxf(acc[mm][0][r], 0.f) + H[o];
                out[o + 16] = fmaxf(acc[mm][1][r], 0.f) + H[o + 16];
            }
        }
}

extern "C" void kernel_launch(void* const* d_in, const int* in_sizes, int n_in,
                              void* d_out, int out_size, void* d_ws, size_t ws_size,
                              hipStream_t stream) {
    const float* H   = (const float*)d_in[0];
    const int*   idx = (const int*)d_in[1];
    const float* Xe  = (const float*)d_in[2];
    const float* W1  = (const float*)d_in[3];
    const float* W2  = (const float*)d_in[4];
    float* out = (float*)d_out;

    // ---- workspace layout (core 32.4 MB; aux tail -> 45.3 MB)
    char* ws = (char*)d_ws;
    float* gmax   = (float*)(ws);                            // 25,600,000
    int*   deg    = (int*)(ws + 25600000);                   // 200,000 (scan_c -> cursor)
    int*   sc     = (int*)(ws + 25800192);                   // 200,000
    int*   totals = (int*)(ws + 26000384);                   // 512
    unsigned long long* pk8 = (unsigned long long*)(ws + 26000896); // 6,400,000
    unsigned short* W1t = (unsigned short*)(ws + 32400896);  // 49,152
    unsigned short* W2t = (unsigned short*)(ws + 32450048);  // 65,536
    unsigned short* Hb  = (unsigned short*)(ws + 32515584);  // 12,800,000
    const int useAux = (ws_size >= (size_t)45315584) ? 1 : 0;

    zero_ws<<<(NG4 + ND4 + 255) / 256, 256, 0, stream>>>(gmax, deg);
    if (useAux)
        conv_aux<<<(NHB4 + NW1 + NW2 + 255) / 256, 256, 0, stream>>>(H, W1, W2, Hb, W1t, W2t);
    hist<<<N_EDGES / 256, 256, 0, stream>>>(idx, deg);
    scan_a<<<N_CHUNKS, SCAN_B, 0, stream>>>(deg, sc, totals);
    scan_b<<<1, 128, 0, stream>>>(totals);
    scan_c<<<N_CHUNKS, SCAN_B, 0, stream>>>(sc, totals, deg);
    scatter<<<N_EDGES / 256, 256, 0, stream>>>(idx, deg, pk8);
    edge_sorted<<<N_EBLK, 512, 0, stream>>>(H, Hb, Xe, W1, W1t, pk8, gmax, useAux);
    node_mlp<<<(N_NODES + 63) / 64, 256, 0, stream>>>(H, gmax, W2, W2t, out, useAux);
}

// Round 12
// 273.735 us; speedup vs baseline: 1.1641x; 1.1641x over previous
//
#include <hip/hip_runtime.h>
#include <hip/hip_bf16.h>
#include <stdint.h>

#define N_NODES 50000
#define N_EDGES 800000
#define D_H 128
#define D_E 64
#define HID 128

#define MTILE 48
#define SMAX 16
#define N_ETILES ((N_EDGES + MTILE - 1) / MTILE)     // 16667

#define SCAN_B 512
#define N_CHUNKS ((N_NODES + SCAN_B - 1) / SCAN_B)   // 98

typedef __attribute__((ext_vector_type(8))) short bf16x8;
typedef __attribute__((ext_vector_type(4))) short s16x4;
typedef __attribute__((ext_vector_type(4))) float f32x4;
typedef __attribute__((ext_vector_type(4))) int i32x4;

__device__ __forceinline__ unsigned short f2bf(float x) {
    unsigned int u = __float_as_uint(x);
    u += 0x7FFFu + ((u >> 16) & 1u);   // round-to-nearest-even
    return (unsigned short)(u >> 16);
}

__device__ __forceinline__ s16x4 pack4(const f32x4 v) {
    s16x4 o = { (short)f2bf(v[0]), (short)f2bf(v[1]),
                (short)f2bf(v[2]), (short)f2bf(v[3]) };
    return o;
}

__device__ __forceinline__ bf16x8 pack8(const f32x4 a, const f32x4 b) {
    bf16x8 o = { (short)f2bf(a[0]), (short)f2bf(a[1]), (short)f2bf(a[2]), (short)f2bf(a[3]),
                 (short)f2bf(b[0]), (short)f2bf(b[1]), (short)f2bf(b[2]), (short)f2bf(b[3]) };
    return o;
}

// ---------------- zero: gmax (f32) + deg ----------------
#define NG4 (N_NODES * HID / 4)
#define ND4 (N_NODES / 4)
__global__ void zero_ws(float* __restrict__ gmax, int* __restrict__ deg) {
    const int i = blockIdx.x * blockDim.x + threadIdx.x;
    if (i < NG4) {
        ((f32x4*)gmax)[i] = f32x4{0.f, 0.f, 0.f, 0.f};
    } else if (i < NG4 + ND4) {
        ((i32x4*)deg)[i - NG4] = i32x4{0, 0, 0, 0};
    }
}

// ---------------- converts: Hb + W1t + W2t ----------------
#define NHB4 (N_NODES * D_H / 4)
#define NW1 (192 * HID)
#define NW2 (256 * HID)
__global__ void conv_aux(const float* __restrict__ H,
                         const float* __restrict__ W1,
                         const float* __restrict__ W2,
                         unsigned short* __restrict__ Hb,
                         unsigned short* __restrict__ W1t,
                         unsigned short* __restrict__ W2t) {
    const int i = blockIdx.x * blockDim.x + threadIdx.x;
    if (i < NHB4) {
        ((s16x4*)Hb)[i] = pack4(((const f32x4*)H)[i]);
    } else if (i < NHB4 + NW1) {                     // W1t [128][192] bf16
        const int j = i - NHB4;
        const int n = j / 192, k = j - n * 192;
        W1t[j] = f2bf(W1[k * HID + n]);
    } else if (i < NHB4 + NW1 + NW2) {               // W2t [128][256] bf16
        const int j = i - NHB4 - NW1;
        const int n = j >> 8, k = j & 255;
        W2t[j] = f2bf(W2[k * HID + n]);
    }
}

// ---------------- histogram ----------------
__global__ void hist(const int* __restrict__ idx, int* __restrict__ deg) {
    const int i = blockIdx.x * blockDim.x + threadIdx.x;
    atomicAdd(&deg[idx[N_EDGES + i]], 1);
}

// ---------------- 3-kernel parallel exclusive scan ----------------
__global__ void scan_a(const int* __restrict__ deg, int* __restrict__ sc,
                       int* __restrict__ totals) {
    __shared__ int s[SCAN_B];
    const int tid = threadIdx.x;
    const int i = blockIdx.x * SCAN_B + tid;
    const int v = (i < N_NODES) ? deg[i] : 0;
    s[tid] = v;
    __syncthreads();
    for (int o = 1; o < SCAN_B; o <<= 1) {
        int t = (tid >= o) ? s[tid - o] : 0;
        __syncthreads();
        s[tid] += t;
        __syncthreads();
    }
    if (i < N_NODES) sc[i] = s[tid] - v;
    if (tid == SCAN_B - 1) totals[blockIdx.x] = s[SCAN_B - 1];
}

__global__ void scan_b(int* __restrict__ totals) {
    __shared__ int s[128];
    const int tid = threadIdx.x;
    const int v = (tid < N_CHUNKS) ? totals[tid] : 0;
    s[tid] = v;
    __syncthreads();
    for (int o = 1; o < 128; o <<= 1) {
        int t = (tid >= o) ? s[tid - o] : 0;
        __syncthreads();
        s[tid] += t;
        __syncthreads();
    }
    if (tid < N_CHUNKS) totals[tid] = s[tid] - v;
}

__global__ void scan_c(const int* __restrict__ sc, const int* __restrict__ totals,
                       int* __restrict__ cursor) {
    const int i = blockIdx.x * SCAN_B + threadIdx.x;
    if (i < N_NODES) cursor[i] = sc[i] + totals[blockIdx.x];
}

// ---------------- scatter: one packed 8B store per edge ----------------
__global__ void scatter(const int* __restrict__ idx, int* __restrict__ cursor,
                        unsigned long long* __restrict__ pk8) {
    int i = blockIdx.x * blockDim.x + threadIdx.x;
    const int s = idx[i];
    const int d = idx[N_EDGES + i];
    const int p = atomicAdd(&cursor[d], 1);
    pk8[p] = (unsigned long long)(unsigned)i |
             ((unsigned long long)(unsigned)s << 20) |
             ((unsigned long long)(unsigned)d << 37);
}

// ---------------- edge MLP: one 48-edge tile per block, 5 blocks/CU ----------------
// LDS ~28 KB -> 5 independent barrier domains per CU (vs 3 at MTILE=96).
// Segmentation fits in wave 0 (48 <= 64): no cross-wave prefix, 2 barriers total.
__global__ __launch_bounds__(256, 5)
void edge_sorted(const float* __restrict__ H,
                 const unsigned short* __restrict__ Hb,
                 const float* __restrict__ Xe,
                 const float* __restrict__ W1,
                 const unsigned short* __restrict__ W1t,
                 const unsigned long long* __restrict__ pk8,
                 float* __restrict__ gmax, int useAux) {
    __shared__ unsigned short sX[MTILE][200];        // 19.2 KB
    __shared__ float ymax[SMAX][132];                // 8.45 KB
    __shared__ int rowD[MTILE];
    __shared__ int segNode[SMAX];
    __shared__ int sNSeg;
    __shared__ unsigned char rowG[MTILE];

    const int tid  = threadIdx.x;
    const int wave = tid >> 6;
    const int lane = tid & 63;
    const int p0   = blockIdx.x * MTILE;

    const int col = lane & 15;
    const int kr0 = (lane >> 4) * 8;

    // --- stage: all gather loads issue before any barrier ---
    if (useAux) {
        #pragma unroll
        for (int it = 0; it < 3; ++it) {
            const int j   = tid + it * 256;          // < 768
            const int row = j >> 4;
            const int c8  = (j & 15) * 8;
            int pe = p0 + row; if (pe >= N_EDGES) pe = N_EDGES - 1;
            const int src = (int)((pk8[pe] >> 20) & 0x1FFFFull);
            *(bf16x8*)&sX[row][c8] = *(const bf16x8*)(Hb + (size_t)src * D_H + c8);
        }
    } else {
        #pragma unroll
        for (int it = 0; it < 6; ++it) {
            const int j   = tid + it * 256;          // < 1536
            const int row = j >> 5;
            const int c4  = (j & 31) * 4;
            int pe = p0 + row; if (pe >= N_EDGES) pe = N_EDGES - 1;
            const int src = (int)((pk8[pe] >> 20) & 0x1FFFFull);
            const f32x4 v = *(const f32x4*)(H + (size_t)src * D_H + c4);
            *(s16x4*)&sX[row][c4] = pack4(v);
        }
    }
    #pragma unroll
    for (int it = 0; it < 2; ++it) {
        const int j = tid + it * 256;                // < 384
        if (j < 384) {
            const int row = j >> 3;
            const int c8  = (j & 7) * 8;
            int pe = p0 + row; if (pe >= N_EDGES) pe = N_EDGES - 1;
            const int e = (int)(pk8[pe] & 0xFFFFFull);
            const float* p = Xe + (size_t)e * D_E + c8;
            *(bf16x8*)&sX[row][128 + c8] = pack8(*(const f32x4*)p, *(const f32x4*)(p + 4));
        }
    }

    // --- ymax zero (pre-barrier) ---
    for (int i2 = tid; i2 < SMAX * 132; i2 += 256) ((float*)ymax)[i2] = 0.f;

    // --- segmentation entirely in wave 0 (tile rows 0..47 < 64) ---
    if (tid < 64) {
        const bool inT  = (tid < MTILE);
        const bool valid = inT && (p0 + tid < N_EDGES);
        int pc = p0 + tid; if (pc >= N_EDGES) pc = N_EDGES - 1;
        int d = 0;
        if (inT) {
            d = (int)(pk8[pc] >> 37);
            rowD[tid] = d;
        }
        int dp = __shfl_up(d, 1);
        const bool flag = valid && (tid == 0 || d != dp);   // row 0 always opens seg 0
        const unsigned long long m = __ballot(flag);
        if (tid == 0) sNSeg = (int)__popcll(m);
        int g = 255;
        if (valid) {
            const unsigned long long le =
                (lane == 63) ? ~0ull : ((1ull << (lane + 1)) - 1);
            g = (int)__popcll(m & le) - 1;
        }
        if (inT) rowG[tid] = (unsigned char)(valid ? g : 255);
        if (flag && g < SMAX) segNode[g] = d;
    }

    // --- B fragments (W1), wave covers cols [wave*32, wave*32+32) ---
    bf16x8 bfrag[6][2];
    if (useAux) {
        #pragma unroll
        for (int ks = 0; ks < 6; ++ks)
            #pragma unroll
            for (int nf = 0; nf < 2; ++nf) {
                const int n = wave * 32 + nf * 16 + col;
                bfrag[ks][nf] = *(const bf16x8*)&W1t[(size_t)n * 192 + ks * 32 + kr0];
            }
    } else {
        #pragma unroll
        for (int ks = 0; ks < 6; ++ks)
            #pragma unroll
            for (int nf = 0; nf < 2; ++nf) {
                const int n  = wave * 32 + nf * 16 + col;
                const int kb = ks * 32 + kr0;
                bf16x8 b;
                #pragma unroll
                for (int f = 0; f < 8; ++f) b[f] = (short)f2bf(W1[(kb + f) * HID + n]);
                bfrag[ks][nf] = b;
            }
    }
    __syncthreads();                                  // B: sX, rowG, segNode, rowD, sNSeg, ymax

    // --- MFMA: 48 x 192 @ 192 x 32 per wave ---
    f32x4 acc[3][2];
    #pragma unroll
    for (int mm = 0; mm < 3; ++mm) {
        acc[mm][0] = f32x4{0.f, 0.f, 0.f, 0.f};
        acc[mm][1] = f32x4{0.f, 0.f, 0.f, 0.f};
    }
    const int arow = lane & 15;
    __builtin_amdgcn_s_setprio(1);
    #pragma unroll
    for (int ks = 0; ks < 6; ++ks)
        #pragma unroll
        for (int mm = 0; mm < 3; ++mm) {
            bf16x8 a = *(const bf16x8*)&sX[mm * 16 + arow][ks * 32 + kr0];
            acc[mm][0] = __builtin_amdgcn_mfma_f32_16x16x32_bf16(a, bfrag[ks][0], acc[mm][0], 0, 0, 0);
            acc[mm][1] = __builtin_amdgcn_mfma_f32_16x16x32_bf16(a, bfrag[ks][1], acc[mm][1], 0, 0, 0);
        }
    __builtin_amdgcn_s_setprio(0);

    // --- relu + segmented max into LDS (overflow -> direct global atomics) ---
    const int rb = (lane >> 4) * 4;
    const int cb = wave * 32 + col;
    #pragma unroll
    for (int mm = 0; mm < 3; ++mm) {
        const int r0 = mm * 16 + rb;
        const int q0 = rowG[r0];
        const int q3 = rowG[r0 + 3];
        if (q0 == q3) {
            const float v0 = fmaxf(fmaxf(acc[mm][0][0], acc[mm][0][1]),
                                   fmaxf(acc[mm][0][2], acc[mm][0][3]));
            const float v1 = fmaxf(fmaxf(acc[mm][1][0], acc[mm][1][1]),
                                   fmaxf(acc[mm][1][2], acc[mm][1][3]));
            if (q0 < SMAX) {
                if (v0 > 0.f) atomicMax((int*)&ymax[q0][cb],      __float_as_int(v0));
                if (v1 > 0.f) atomicMax((int*)&ymax[q0][cb + 16], __float_as_int(v1));
            } else if (q0 < 255) {
                float* base = gmax + (size_t)rowD[r0] * HID;
                if (v0 > 0.f) atomicMax((int*)(base + cb),      __float_as_int(v0));
                if (v1 > 0.f) atomicMax((int*)(base + cb + 16), __float_as_int(v1));
            }
        } else {
            #pragma unroll
            for (int r = 0; r < 4; ++r) {
                const int qq = rowG[r0 + r];
                const float v0 = acc[mm][0][r];
                const float v1 = acc[mm][1][r];
                if (qq < SMAX) {
                    if (v0 > 0.f) atomicMax((int*)&ymax[qq][cb],      __float_as_int(v0));
                    if (v1 > 0.f) atomicMax((int*)&ymax[qq][cb + 16], __float_as_int(v1));
                } else if (qq < 255) {
                    float* base = gmax + (size_t)rowD[r0 + r] * HID;
                    if (v0 > 0.f) atomicMax((int*)(base + cb),      __float_as_int(v0));
                    if (v1 > 0.f) atomicMax((int*)(base + cb + 16), __float_as_int(v1));
                }
            }
        }
    }
    __syncthreads();                                  // C: ymax complete

    // --- writeout: vectorized; interior plain store, first/last atomicMax ---
    const int nSeg = sNSeg;
    const int nS = (nSeg < SMAX) ? nSeg : SMAX;
    for (int i2 = tid; i2 < nS * 32; i2 += 256) {
        const int sg = i2 >> 5;
        const int c4 = (i2 & 31) * 4;
        float* dst = gmax + (size_t)segNode[sg] * HID + c4;
        const f32x4 v = *(const f32x4*)&ymax[sg][c4];
        if (sg == 0 || sg == nSeg - 1) {
            #pragma unroll
            for (int q = 0; q < 4; ++q)
                if (v[q] > 0.f) atomicMax((int*)(dst + q), __float_as_int(v[q]));
        } else {
            *(f32x4*)dst = v;
        }
    }
}

// ---------------- node MLP + residual ----------------
__global__ __launch_bounds__(256, 4)
void node_mlp(const float* __restrict__ H,
              const float* __restrict__ gmax,
              const float* __restrict__ W2,
              const unsigned short* __restrict__ W2t,
              float* __restrict__ out, int useAux) {
    __shared__ unsigned short sA[64][264];

    const int tid  = threadIdx.x;
    const int wave = tid >> 6;
    const int lane = tid & 63;
    const int base = blockIdx.x * 64;

    const int col = lane & 15;
    const int kr0 = (lane >> 4) * 8;
    bf16x8 bfrag[8][2];
    if (useAux) {
        #pragma unroll
        for (int ks = 0; ks < 8; ++ks)
            #pragma unroll
            for (int nf = 0; nf < 2; ++nf) {
                const int n = wave * 32 + nf * 16 + col;
                bfrag[ks][nf] = *(const bf16x8*)&W2t[(size_t)n * 256 + ks * 32 + kr0];
            }
    } else {
        #pragma unroll
        for (int ks = 0; ks < 8; ++ks)
            #pragma unroll
            for (int nf = 0; nf < 2; ++nf) {
                const int n  = wave * 32 + nf * 16 + col;
                const int kb = ks * 32 + kr0;
                bf16x8 b;
                #pragma unroll
                for (int f = 0; f < 8; ++f) b[f] = (short)f2bf(W2[(kb + f) * HID + n]);
                bfrag[ks][nf] = b;
            }
    }

    #pragma unroll
    for (int it = 0; it < 8; ++it) {
        const int i   = tid + it * 256;
        const int row = i >> 5;
        const int c4  = (i & 31) * 4;
        int node = base + row;
        if (node >= N_NODES) node = N_NODES - 1;
        *(s16x4*)&sA[row][c4] = pack4(*(const f32x4*)(H + (size_t)node * D_H + c4));
    }
    #pragma unroll
    for (int it = 0; it < 8; ++it) {
        const int i   = tid + it * 256;
        const int row = i >> 5;
        const int c4  = (i & 31) * 4;
        int node = base + row;
        if (node >= N_NODES) node = N_NODES - 1;
        *(s16x4*)&sA[row][128 + c4] = pack4(*(const f32x4*)(gmax + (size_t)node * HID + c4));
    }
    __syncthreads();

    f32x4 acc[4][2];
    #pragma unroll
    for (int mm = 0; mm < 4; ++mm) {
        acc[mm][0] = f32x4{0.f, 0.f, 0.f, 0.f};
        acc[mm][1] = f32x4{0.f, 0.f, 0.f, 0.f};
    }
    const int arow = lane & 15;
    __builtin_amdgcn_s_setprio(1);
    #pragma unroll
    for (int ks = 0; ks < 8; ++ks)
        #pragma unroll
        for (int mm = 0; mm < 4; ++mm) {
            bf16x8 a = *(const bf16x8*)&sA[mm * 16 + arow][ks * 32 + kr0];
            acc[mm][0] = __builtin_amdgcn_mfma_f32_16x16x32_bf16(a, bfrag[ks][0], acc[mm][0], 0, 0, 0);
            acc[mm][1] = __builtin_amdgcn_mfma_f32_16x16x32_bf16(a, bfrag[ks][1], acc[mm][1], 0, 0, 0);
        }
    __builtin_amdgcn_s_setprio(0);

    const int rb = (lane >> 4) * 4;
    #pragma unroll
    for (int mm = 0; mm < 4; ++mm)
        #pragma unroll
        for (int r = 0; r < 4; ++r) {
            const int node = base + mm * 16 + rb + r;
            if (node < N_NODES) {
                const size_t o = (size_t)node * HID + wave * 32 + col;
                out[o]      = fmaxf(acc[mm][0][r], 0.f) + H[o];
                out[o + 16] = fmaxf(acc[mm][1][r], 0.f) + H[o + 16];
            }
        }
}

extern "C" void kernel_launch(void* const* d_in, const int* in_sizes, int n_in,
                              void* d_out, int out_size, void* d_ws, size_t ws_size,
                              hipStream_t stream) {
    const float* H   = (const float*)d_in[0];
    const int*   idx = (const int*)d_in[1];
    const float* Xe  = (const float*)d_in[2];
    const float* W1  = (const float*)d_in[3];
    const float* W2  = (const float*)d_in[4];
    float* out = (float*)d_out;

    // ---- workspace layout (core 32.4 MB; aux tail -> 45.3 MB)
    char* ws = (char*)d_ws;
    float* gmax   = (float*)(ws);                            // 25,600,000
    int*   deg    = (int*)(ws + 25600000);                   // 200,000 (scan_c -> cursor)
    int*   sc     = (int*)(ws + 25800192);                   // 200,000
    int*   totals = (int*)(ws + 26000384);                   // 512
    unsigned long long* pk8 = (unsigned long long*)(ws + 26000896); // 6,400,000
    unsigned short* W1t = (unsigned short*)(ws + 32400896);  // 49,152
    unsigned short* W2t = (unsigned short*)(ws + 32450048);  // 65,536
    unsigned short* Hb  = (unsigned short*)(ws + 32515584);  // 12,800,000
    const int useAux = (ws_size >= (size_t)45315584) ? 1 : 0;

    zero_ws<<<(NG4 + ND4 + 255) / 256, 256, 0, stream>>>(gmax, deg);
    if (useAux)
        conv_aux<<<(NHB4 + NW1 + NW2 + 255) / 256, 256, 0, stream>>>(H, W1, W2, Hb, W1t, W2t);
    hist<<<N_EDGES / 256, 256, 0, stream>>>(idx, deg);
    scan_a<<<N_CHUNKS, SCAN_B, 0, stream>>>(deg, sc, totals);
    scan_b<<<1, 128, 0, stream>>>(totals);
    scan_c<<<N_CHUNKS, SCAN_B, 0, stream>>>(sc, totals, deg);
    scatter<<<N_EDGES / 256, 256, 0, stream>>>(idx, deg, pk8);
    edge_sorted<<<N_ETILES, 256, 0, stream>>>(H, Hb, Xe, W1, W1t, pk8, gmax, useAux);
    node_mlp<<<(N_NODES + 63) / 64, 256, 0, stream>>>(H, gmax, W2, W2t, out, useAux);
}

// Round 13
// 250.867 us; speedup vs baseline: 1.2702x; 1.0912x over previous
//
#include <hip/hip_runtime.h>
#include <hip/hip_bf16.h>
#include <stdint.h>

#define N_NODES 50000
#define N_EDGES 800000
#define D_H 128
#define D_E 64
#define HID 128

#define MTILE 96
#define SMAX 16
#define N_ETILES ((N_EDGES + MTILE - 1) / MTILE)     // 8334

#define SCAN_B 512
#define N_CHUNKS ((N_NODES + SCAN_B - 1) / SCAN_B)   // 98

typedef __attribute__((ext_vector_type(8))) short bf16x8;
typedef __attribute__((ext_vector_type(4))) short s16x4;
typedef __attribute__((ext_vector_type(4))) float f32x4;
typedef __attribute__((ext_vector_type(4))) int i32x4;

__device__ __forceinline__ unsigned short f2bf(float x) {
    unsigned int u = __float_as_uint(x);
    u += 0x7FFFu + ((u >> 16) & 1u);   // round-to-nearest-even
    return (unsigned short)(u >> 16);
}

__device__ __forceinline__ s16x4 pack4(const f32x4 v) {
    s16x4 o = { (short)f2bf(v[0]), (short)f2bf(v[1]),
                (short)f2bf(v[2]), (short)f2bf(v[3]) };
    return o;
}

__device__ __forceinline__ bf16x8 pack8(const f32x4 a, const f32x4 b) {
    bf16x8 o = { (short)f2bf(a[0]), (short)f2bf(a[1]), (short)f2bf(a[2]), (short)f2bf(a[3]),
                 (short)f2bf(b[0]), (short)f2bf(b[1]), (short)f2bf(b[2]), (short)f2bf(b[3]) };
    return o;
}

// ---------------- fused prep: {gmax,deg} zero ++ {Hb,W1t,W2t} convert ----------------
#define NG4 (N_NODES * HID / 4)          // 1,600,000 f32x4
#define ND4 (N_NODES / 4)                // 12,500 i32x4
#define NHB4 (N_NODES * D_H / 4)         // 1,600,000 s16x4
#define NW1 (192 * HID)                  // 24,576
#define NW2 (256 * HID)                  // 32,768
#define ZB  ((NG4 + ND4 + 255) / 256)              // 6299 blocks (zero part)
#define CB  ((NHB4 + NW1 + NW2 + 255) / 256)       // 6474 blocks (conv part)
__global__ void prep0(const float* __restrict__ H,
                      const float* __restrict__ W1,
                      const float* __restrict__ W2,
                      float* __restrict__ gmax, int* __restrict__ deg,
                      unsigned short* __restrict__ Hb,
                      unsigned short* __restrict__ W1t,
                      unsigned short* __restrict__ W2t) {
    const int b = blockIdx.x;
    if (b < ZB) {
        const int i = b * 256 + threadIdx.x;
        if (i < NG4) {
            ((f32x4*)gmax)[i] = f32x4{0.f, 0.f, 0.f, 0.f};
        } else if (i < NG4 + ND4) {
            ((i32x4*)deg)[i - NG4] = i32x4{0, 0, 0, 0};
        }
    } else {
        const int i = (b - ZB) * 256 + threadIdx.x;
        if (i < NHB4) {
            ((s16x4*)Hb)[i] = pack4(((const f32x4*)H)[i]);
        } else if (i < NHB4 + NW1) {                 // W1t [128][192] bf16
            const int j = i - NHB4;
            const int n = j / 192, k = j - n * 192;
            W1t[j] = f2bf(W1[k * HID + n]);
        } else if (i < NHB4 + NW1 + NW2) {           // W2t [128][256] bf16
            const int j = i - NHB4 - NW1;
            const int n = j >> 8, k = j & 255;
            W2t[j] = f2bf(W2[k * HID + n]);
        }
    }
}

// ---------------- histogram: 4 edges/thread ----------------
__global__ void hist(const int* __restrict__ idx, int* __restrict__ deg) {
    const int i = blockIdx.x * blockDim.x + threadIdx.x;
    if (i < N_EDGES / 4) {
        const i32x4 d4 = ((const i32x4*)(idx + N_EDGES))[i];
        atomicAdd(&deg[d4.x], 1);
        atomicAdd(&deg[d4.y], 1);
        atomicAdd(&deg[d4.z], 1);
        atomicAdd(&deg[d4.w], 1);
    }
}

// ---------------- 3-kernel parallel exclusive scan ----------------
__global__ void scan_a(const int* __restrict__ deg, int* __restrict__ sc,
                       int* __restrict__ totals) {
    __shared__ int s[SCAN_B];
    const int tid = threadIdx.x;
    const int i = blockIdx.x * SCAN_B + tid;
    const int v = (i < N_NODES) ? deg[i] : 0;
    s[tid] = v;
    __syncthreads();
    for (int o = 1; o < SCAN_B; o <<= 1) {
        int t = (tid >= o) ? s[tid - o] : 0;
        __syncthreads();
        s[tid] += t;
        __syncthreads();
    }
    if (i < N_NODES) sc[i] = s[tid] - v;
    if (tid == SCAN_B - 1) totals[blockIdx.x] = s[SCAN_B - 1];
}

__global__ void scan_b(int* __restrict__ totals) {
    __shared__ int s[128];
    const int tid = threadIdx.x;
    const int v = (tid < N_CHUNKS) ? totals[tid] : 0;
    s[tid] = v;
    __syncthreads();
    for (int o = 1; o < 128; o <<= 1) {
        int t = (tid >= o) ? s[tid - o] : 0;
        __syncthreads();
        s[tid] += t;
        __syncthreads();
    }
    if (tid < N_CHUNKS) totals[tid] = s[tid] - v;
}

__global__ void scan_c(const int* __restrict__ sc, const int* __restrict__ totals,
                       int* __restrict__ cursor) {
    const int i = blockIdx.x * SCAN_B + threadIdx.x;
    if (i < N_NODES) cursor[i] = sc[i] + totals[blockIdx.x];
}

// ---------------- scatter: 4 edges/thread, packed 8B store per edge ----------------
__global__ void scatter(const int* __restrict__ idx, int* __restrict__ cursor,
                        unsigned long long* __restrict__ pk8) {
    const int i = blockIdx.x * blockDim.x + threadIdx.x;
    if (i < N_EDGES / 4) {
        const i32x4 s4 = ((const i32x4*)idx)[i];
        const i32x4 d4 = ((const i32x4*)(idx + N_EDGES))[i];
        #pragma unroll
        for (int q = 0; q < 4; ++q) {
            const int e = i * 4 + q;
            const int s = (q == 0) ? s4.x : (q == 1) ? s4.y : (q == 2) ? s4.z : s4.w;
            const int d = (q == 0) ? d4.x : (q == 1) ? d4.y : (q == 2) ? d4.z : d4.w;
            const int p = atomicAdd(&cursor[d], 1);
            pk8[p] = (unsigned long long)(unsigned)e |
                     ((unsigned long long)(unsigned)s << 20) |
                     ((unsigned long long)(unsigned)d << 37);
        }
    }
}

// ---------------- edge MLP, one 96-edge tile per block (R8 proven) ----------------
__global__ __launch_bounds__(256, 3)
void edge_sorted(const float* __restrict__ H,
                 const unsigned short* __restrict__ Hb,
                 const float* __restrict__ Xe,
                 const float* __restrict__ W1,
                 const unsigned short* __restrict__ W1t,
                 const unsigned long long* __restrict__ pk8,
                 float* __restrict__ gmax, int useAux) {
    __shared__ unsigned short sX[MTILE][200];        // 38.4 KB
    __shared__ float ymax[SMAX + 1][132];            // 9.0 KB
    __shared__ int rowD[MTILE];
    __shared__ int segNode[SMAX];
    __shared__ int sWaveTot[4];
    __shared__ unsigned char rowG[MTILE];

    const int tid  = threadIdx.x;
    const int wave = tid >> 6;
    const int lane = tid & 63;
    const int p0   = blockIdx.x * MTILE;

    const int col = lane & 15;
    const int kr0 = (lane >> 4) * 8;

    // --- stage issues first: all gather loads go out before any barrier ---
    if (useAux) {
        #pragma unroll
        for (int it = 0; it < 6; ++it) {
            const int j   = tid + it * 256;          // < 1536
            const int row = j >> 4;
            const int c8  = (j & 15) * 8;
            int pe = p0 + row; if (pe >= N_EDGES) pe = N_EDGES - 1;
            const int src = (int)((pk8[pe] >> 20) & 0x1FFFFull);
            *(bf16x8*)&sX[row][c8] = *(const bf16x8*)(Hb + (size_t)src * D_H + c8);
        }
    } else {
        #pragma unroll
        for (int it = 0; it < 12; ++it) {
            const int j   = tid + it * 256;          // < 3072
            const int row = j >> 5;
            const int c4  = (j & 31) * 4;
            int pe = p0 + row; if (pe >= N_EDGES) pe = N_EDGES - 1;
            const int src = (int)((pk8[pe] >> 20) & 0x1FFFFull);
            const f32x4 v = *(const f32x4*)(H + (size_t)src * D_H + c4);
            *(s16x4*)&sX[row][c4] = pack4(v);
        }
    }
    #pragma unroll
    for (int it = 0; it < 3; ++it) {
        const int j   = tid + it * 256;              // < 768
        const int row = j >> 3;
        const int c8  = (j & 7) * 8;
        int pe = p0 + row; if (pe >= N_EDGES) pe = N_EDGES - 1;
        const int e = (int)(pk8[pe] & 0xFFFFFull);
        const float* p = Xe + (size_t)e * D_E + c8;
        *(bf16x8*)&sX[row][128 + c8] = pack8(*(const f32x4*)p, *(const f32x4*)(p + 4));
    }

    // --- B fragments (W1), wave covers cols [wave*32, wave*32+32)
    bf16x8 bfrag[6][2];
    if (useAux) {
        #pragma unroll
        for (int ks = 0; ks < 6; ++ks)
            #pragma unroll
            for (int nf = 0; nf < 2; ++nf) {
                const int n = wave * 32 + nf * 16 + col;
                bfrag[ks][nf] = *(const bf16x8*)&W1t[(size_t)n * 192 + ks * 32 + kr0];
            }
    } else {
        #pragma unroll
        for (int ks = 0; ks < 6; ++ks)
            #pragma unroll
            for (int nf = 0; nf < 2; ++nf) {
                const int n  = wave * 32 + nf * 16 + col;
                const int kb = ks * 32 + kr0;
                bf16x8 b;
                #pragma unroll
                for (int f = 0; f < 8; ++f) b[f] = (short)f2bf(W1[(kb + f) * HID + n]);
                bfrag[ks][nf] = b;
            }
    }

    // --- tile-local segmentation ---
    const int pe0 = p0 + tid;
    const bool inTile = (tid < MTILE);
    const bool valid  = inTile && (pe0 < N_EDGES);
    int d = 0;
    if (inTile) {
        const int pc = valid ? pe0 : (N_EDGES - 1);
        d = (int)(pk8[pc] >> 37);
        rowD[tid] = d;
    }
    int dp = __shfl_up(d, 1);
    if (lane == 0 && inTile && tid > 0) dp = (int)(pk8[pe0 - 1] >> 37);
    const bool flag = valid && (tid == 0 || d != dp);
    const unsigned long long m = __ballot(flag);
    if (lane == 0) sWaveTot[wave] = (int)__popcll(m);

    for (int i2 = tid; i2 < (SMAX + 1) * 132; i2 += 256) ((float*)ymax)[i2] = 0.f;
    __syncthreads();                                  // A: sWaveTot ready

    int g = 255;
    if (valid) {
        const unsigned long long le =
            (lane == 63) ? ~0ull : ((1ull << (lane + 1)) - 1);
        g = (int)__popcll(m & le) - 1 + ((wave == 1) ? sWaveTot[0] : 0);
    }
    if (inTile) rowG[tid] = (unsigned char)(valid ? g : 255);
    if (flag && g < SMAX) segNode[g] = d;
    __syncthreads();                                  // B: sX + rowG + segNode ready

    // --- MFMA: 96 x 192 @ 192 x 32 per wave
    f32x4 acc[6][2];
    #pragma unroll
    for (int mm = 0; mm < 6; ++mm) {
        acc[mm][0] = f32x4{0.f, 0.f, 0.f, 0.f};
        acc[mm][1] = f32x4{0.f, 0.f, 0.f, 0.f};
    }
    const int arow = lane & 15;
    __builtin_amdgcn_s_setprio(1);
    #pragma unroll
    for (int ks = 0; ks < 6; ++ks)
        #pragma unroll
        for (int mm = 0; mm < 6; ++mm) {
            bf16x8 a = *(const bf16x8*)&sX[mm * 16 + arow][ks * 32 + kr0];
            acc[mm][0] = __builtin_amdgcn_mfma_f32_16x16x32_bf16(a, bfrag[ks][0], acc[mm][0], 0, 0, 0);
            acc[mm][1] = __builtin_amdgcn_mfma_f32_16x16x32_bf16(a, bfrag[ks][1], acc[mm][1], 0, 0, 0);
        }
    __builtin_amdgcn_s_setprio(0);

    // --- relu + segmented max into LDS (overflow segs -> direct global atomics)
    const int rb = (lane >> 4) * 4;
    const int cb = wave * 32 + col;
    #pragma unroll
    for (int mm = 0; mm < 6; ++mm) {
        const int r0 = mm * 16 + rb;
        const int g0 = rowG[r0];
        const int g3 = rowG[r0 + 3];
        if (g0 == g3) {
            const float v0 = fmaxf(fmaxf(acc[mm][0][0], acc[mm][0][1]),
                                   fmaxf(acc[mm][0][2], acc[mm][0][3]));
            const float v1 = fmaxf(fmaxf(acc[mm][1][0], acc[mm][1][1]),
                                   fmaxf(acc[mm][1][2], acc[mm][1][3]));
            if (g0 < SMAX) {
                if (v0 > 0.f) atomicMax((int*)&ymax[g0][cb],      __float_as_int(v0));
                if (v1 > 0.f) atomicMax((int*)&ymax[g0][cb + 16], __float_as_int(v1));
            } else if (g0 < 255) {
                float* base = gmax + (size_t)rowD[r0] * HID;
                if (v0 > 0.f) atomicMax((int*)(base + cb),      __float_as_int(v0));
                if (v1 > 0.f) atomicMax((int*)(base + cb + 16), __float_as_int(v1));
            }
        } else {
            #pragma unroll
            for (int r = 0; r < 4; ++r) {
                const int gg = rowG[r0 + r];
                const float v0 = acc[mm][0][r];
                const float v1 = acc[mm][1][r];
                if (gg < SMAX) {
                    if (v0 > 0.f) atomicMax((int*)&ymax[gg][cb],      __float_as_int(v0));
                    if (v1 > 0.f) atomicMax((int*)&ymax[gg][cb + 16], __float_as_int(v1));
                } else if (gg < 255) {
                    float* base = gmax + (size_t)rowD[r0 + r] * HID;
                    if (v0 > 0.f) atomicMax((int*)(base + cb),      __float_as_int(v0));
                    if (v1 > 0.f) atomicMax((int*)(base + cb + 16), __float_as_int(v1));
                }
            }
        }
    }
    __syncthreads();                                  // C: ymax ready

    // --- writeout: interior segments plain store, first/last atomicMax
    const int nSeg = sWaveTot[0] + sWaveTot[1];
    const int nS = (nSeg < SMAX) ? nSeg : SMAX;
    for (int i2 = tid; i2 < nS * 128; i2 += 256) {
        const int sg = i2 >> 7;
        const int c  = i2 & 127;
        const float v = ymax[sg][c];
        float* dst = gmax + (size_t)segNode[sg] * HID + c;
        if (sg == 0 || sg == nSeg - 1) {
            if (v > 0.f) atomicMax((int*)dst, __float_as_int(v));
        } else {
            *dst = v;
        }
    }
}

// ---------------- node MLP + residual (R8 proven) ----------------
__global__ __launch_bounds__(256, 4)
void node_mlp(const float* __restrict__ H,
              const float* __restrict__ gmax,
              const float* __restrict__ W2,
              const unsigned short* __restrict__ W2t,
              float* __restrict__ out, int useAux) {
    __shared__ unsigned short sA[64][264];

    const int tid  = threadIdx.x;
    const int wave = tid >> 6;
    const int lane = tid & 63;
    const int base = blockIdx.x * 64;

    const int col = lane & 15;
    const int kr0 = (lane >> 4) * 8;
    bf16x8 bfrag[8][2];
    if (useAux) {
        #pragma unroll
        for (int ks = 0; ks < 8; ++ks)
            #pragma unroll
            for (int nf = 0; nf < 2; ++nf) {
                const int n = wave * 32 + nf * 16 + col;
                bfrag[ks][nf] = *(const bf16x8*)&W2t[(size_t)n * 256 + ks * 32 + kr0];
            }
    } else {
        #pragma unroll
        for (int ks = 0; ks < 8; ++ks)
            #pragma unroll
            for (int nf = 0; nf < 2; ++nf) {
                const int n  = wave * 32 + nf * 16 + col;
                const int kb = ks * 32 + kr0;
                bf16x8 b;
                #pragma unroll
                for (int f = 0; f < 8; ++f) b[f] = (short)f2bf(W2[(kb + f) * HID + n]);
                bfrag[ks][nf] = b;
            }
    }

    #pragma unroll
    for (int it = 0; it < 8; ++it) {
        const int i   = tid + it * 256;
        const int row = i >> 5;
        const int c4  = (i & 31) * 4;
        int node = base + row;
        if (node >= N_NODES) node = N_NODES - 1;
        *(s16x4*)&sA[row][c4] = pack4(*(const f32x4*)(H + (size_t)node * D_H + c4));
    }
    #pragma unroll
    for (int it = 0; it < 8; ++it) {
        const int i   = tid + it * 256;
        const int row = i >> 5;
        const int c4  = (i & 31) * 4;
        int node = base + row;
        if (node >= N_NODES) node = N_NODES - 1;
        *(s16x4*)&sA[row][128 + c4] = pack4(*(const f32x4*)(gmax + (size_t)node * HID + c4));
    }
    __syncthreads();

    f32x4 acc[4][2];
    #pragma unroll
    for (int mm = 0; mm < 4; ++mm) {
        acc[mm][0] = f32x4{0.f, 0.f, 0.f, 0.f};
        acc[mm][1] = f32x4{0.f, 0.f, 0.f, 0.f};
    }
    const int arow = lane & 15;
    __builtin_amdgcn_s_setprio(1);
    #pragma unroll
    for (int ks = 0; ks < 8; ++ks)
        #pragma unroll
        for (int mm = 0; mm < 4; ++mm) {
            bf16x8 a = *(const bf16x8*)&sA[mm * 16 + arow][ks * 32 + kr0];
            acc[mm][0] = __builtin_amdgcn_mfma_f32_16x16x32_bf16(a, bfrag[ks][0], acc[mm][0], 0, 0, 0);
            acc[mm][1] = __builtin_amdgcn_mfma_f32_16x16x32_bf16(a, bfrag[ks][1], acc[mm][1], 0, 0, 0);
        }
    __builtin_amdgcn_s_setprio(0);

    const int rb = (lane >> 4) * 4;
    #pragma unroll
    for (int mm = 0; mm < 4; ++mm)
        #pragma unroll
        for (int r = 0; r < 4; ++r) {
            const int node = base + mm * 16 + rb + r;
            if (node < N_NODES) {
                const size_t o = (size_t)node * HID + wave * 32 + col;
                out[o]      = fmaxf(acc[mm][0][r], 0.f) + H[o];
                out[o + 16] = fmaxf(acc[mm][1][r], 0.f) + H[o + 16];
            }
        }
}

extern "C" void kernel_launch(void* const* d_in, const int* in_sizes, int n_in,
                              void* d_out, int out_size, void* d_ws, size_t ws_size,
                              hipStream_t stream) {
    const float* H   = (const float*)d_in[0];
    const int*   idx = (const int*)d_in[1];
    const float* Xe  = (const float*)d_in[2];
    const float* W1  = (const float*)d_in[3];
    const float* W2  = (const float*)d_in[4];
    float* out = (float*)d_out;

    // ---- workspace layout (core 32.4 MB; aux tail -> 45.3 MB)
    char* ws = (char*)d_ws;
    float* gmax   = (float*)(ws);                            // 25,600,000
    int*   deg    = (int*)(ws + 25600000);                   // 200,000 (scan_c -> cursor)
    int*   sc     = (int*)(ws + 25800192);                   // 200,000
    int*   totals = (int*)(ws + 26000384);                   // 512
    unsigned long long* pk8 = (unsigned long long*)(ws + 26000896); // 6,400,000
    unsigned short* W1t = (unsigned short*)(ws + 32400896);  // 49,152
    unsigned short* W2t = (unsigned short*)(ws + 32450048);  // 65,536
    unsigned short* Hb  = (unsigned short*)(ws + 32515584);  // 12,800,000
    const int useAux = (ws_size >= (size_t)45315584) ? 1 : 0;

    const int nPrep = ZB + (useAux ? CB : 0);
    prep0<<<nPrep, 256, 0, stream>>>(H, W1, W2, gmax, deg, Hb, W1t, W2t);
    hist<<<(N_EDGES / 4 + 255) / 256, 256, 0, stream>>>(idx, deg);
    scan_a<<<N_CHUNKS, SCAN_B, 0, stream>>>(deg, sc, totals);
    scan_b<<<1, 128, 0, stream>>>(totals);
    scan_c<<<N_CHUNKS, SCAN_B, 0, stream>>>(sc, totals, deg);
    scatter<<<(N_EDGES / 4 + 255) / 256, 256, 0, stream>>>(idx, deg, pk8);
    edge_sorted<<<N_ETILES, 256, 0, stream>>>(H, Hb, Xe, W1, W1t, pk8, gmax, useAux);
    node_mlp<<<(N_NODES + 63) / 64, 256, 0, stream>>>(H, gmax, W2, W2t, out, useAux);
}